// Round 12
// baseline (6652.121 us; speedup 1.0000x reference)
//
#include <hip/hip_runtime.h>
#include <hip/hip_bf16.h>
#include <hip/hip_fp16.h>

#define LL    3630
#define EPSV  1e-5f
#define NCH   57      // scan chunks (64-token, matches mamba_pre blocks)
#define CLEN  64

typedef short bf16x8 __attribute__((ext_vector_type(8)));
typedef float f32x4  __attribute__((ext_vector_type(4)));
typedef float f32x2  __attribute__((ext_vector_type(2)));
typedef float f32x16 __attribute__((ext_vector_type(16)));

__device__ __forceinline__ float bf2f(__hip_bfloat16 x){ return __bfloat162float(x); }
__device__ __forceinline__ __hip_bfloat16 f2bf(float x){ return __float2bfloat16(x); }
__device__ __forceinline__ float siluf(float x){ return x / (1.f + __expf(-x)); }
__device__ __forceinline__ float s2f(short s){ __hip_bfloat16 t = __builtin_bit_cast(__hip_bfloat16, s); return __bfloat162float(t); }
__device__ __forceinline__ short f2s(float x){ __hip_bfloat16 t = __float2bfloat16(x); return __builtin_bit_cast(short, t); }

// ======================= weight f32 -> bf16 =======================
__global__ __launch_bounds__(256) void convert_weights(
    const float* __restrict__ s0, const float* __restrict__ s1,
    const float* __restrict__ s2, const float* __restrict__ s3,
    const float* __restrict__ s4, const float* __restrict__ s5,
    const float* __restrict__ s6,
    __hip_bfloat16* __restrict__ dst)
{
  int gid = blockIdx.x*256 + threadIdx.x;
  float v;
  if      (gid <  65536) v = s0[gid];
  else if (gid < 327680) v = s1[gid-65536];
  else if (gid < 458752) v = s2[gid-327680];
  else if (gid < 491520) v = s3[gid-458752];
  else if (gid < 557056) v = s4[gid-491520];
  else if (gid < 622592) v = s5[gid-557056];
  else if (gid < 671744){
    int rel = gid - 622592;
    int layer = rel / 12288;
    int rr  = (rel % 12288) / 256;
    int ccol= rel & 255;
    v = (rr < 40) ? s6[layer*10240 + rr*256 + ccol] : 0.f;
  }
  else return;
  dst[gid] = f2bf(v);
}

// ======================= stem =======================
__global__ __launch_bounds__(256) void stem1_kernel(
    const float* __restrict__ x, const float* __restrict__ w,
    const float* __restrict__ g, const float* __restrict__ bb,
    const float* __restrict__ mm, const float* __restrict__ vv,
    float* __restrict__ out, int nb, int b0)
{
  int idx = blockIdx.x*256 + threadIdx.x;
  if (idx >= nb*123904) return;
  int j = idx % 11;
  int i = (idx/11) % 11;
  int t = (idx/121) % 32;
  int c = (idx/(121*32)) % 32;
  int b = idx/(121*32*32);
  const float* xp = x + ((b0+b)*32 + t)*169;
  const float* wp = w + c*9;
  float acc = 0.f;
  #pragma unroll
  for (int di=0; di<3; ++di)
    #pragma unroll
    for (int dj=0; dj<3; ++dj)
      acc += xp[(i+di)*13 + (j+dj)] * wp[di*3+dj];
  float s = g[c]*rsqrtf(vv[c]+EPSV);
  acc = acc*s + (bb[c]-mm[c]*s);
  out[idx] = fmaxf(acc, 0.f);
}

__global__ __launch_bounds__(256) void stem2_kernel(
    const float* __restrict__ h1, const float* __restrict__ w,
    const float* __restrict__ g, const float* __restrict__ bb,
    const float* __restrict__ mm, const float* __restrict__ vv,
    float* __restrict__ out, int nb)
{
  int idx = blockIdx.x*256 + threadIdx.x;
  if (idx >= nb*116160) return;
  int ij = idx % 121;
  int t  = (idx/121) % 30;
  int c  = (idx/(121*30)) % 32;
  int b  = idx/(121*30*32);
  const float* hp = h1 + ((b*32+c)*32)*121 + ij;
  const float* wp = w + c*3;
  float acc = 0.f;
  #pragma unroll
  for (int k=0;k<3;++k) acc += hp[(t+k)*121] * wp[k];
  float s = g[c]*rsqrtf(vv[c]+EPSV);
  acc = acc*s + (bb[c]-mm[c]*s);
  out[idx] = fmaxf(acc, 0.f);
}

// stem3 + fused LayerNorm (wave = one token, lane = channel)
__global__ __launch_bounds__(256) void stem3_kernel(
    const float* __restrict__ h2, const float* __restrict__ w,
    const float* __restrict__ lng, const float* __restrict__ lnb,
    __hip_bfloat16* __restrict__ xb, __hip_bfloat16* __restrict__ hx, int tokens)
{
  int gid = blockIdx.x*256 + threadIdx.x;
  int cc = gid & 63;
  int tok = gid >> 6;
  if (tok >= tokens) return;
  int ij = tok % 121;
  int t  = (tok/121) % 30;
  int b  = tok/LL;
  const float* hp = h2 + ((long)b*32)*30*121 + t*121 + ij;
  const float* wp = w + cc*32;
  float acc = 0.f;
  #pragma unroll
  for (int ci=0; ci<32; ++ci) acc += hp[ci*3630] * wp[ci];
  xb[(long)tok*64+cc] = f2bf(acc);
  float s = acc, q = acc*acc;
  #pragma unroll
  for (int m=1; m<64; m<<=1){ s += __shfl_xor(s,m); q += __shfl_xor(q,m); }
  float mean = s*(1.f/64.f);
  float var  = q*(1.f/64.f) - mean*mean;
  hx[(long)tok*64+cc] = f2bf((acc-mean)*rsqrtf(var+EPSV)*lng[cc] + lnb[cc]);
}

// ======================= bf16 MFMA GEMM: 128-row blocks + XCD-chunk swizzle =======================
// EPI 0: split silu; EPI 2: bias+gelu; EPI 5 (N=64): (+bias)+resid RMW + LayerNorm
template<int EPI>
__global__ __launch_bounds__(256) void gemm_bf16(
    const __hip_bfloat16* __restrict__ A, const __hip_bfloat16* __restrict__ W,
    int K, int N, int NH, int ny, int tokens,
    __hip_bfloat16* __restrict__ out1, __hip_bfloat16* __restrict__ out2,
    const float* __restrict__ bias, const __hip_bfloat16* __restrict__ gate,
    __hip_bfloat16* __restrict__ resid,
    const float* __restrict__ lng, const float* __restrict__ lnb)
{
  int w   = threadIdx.x >> 6;
  int lane= threadIdx.x & 63;
  int r16 = lane & 15;
  int kg  = lane >> 4;          // 0..3
  int nwg = gridDim.x;
  int orig = blockIdx.x;
  int q = nwg >> 3, r8 = nwg & 7;
  int xcd = orig & 7, off = orig >> 3;
  int wg = (xcd < r8 ? xcd*(q+1) : r8*(q+1) + (xcd-r8)*q) + off;
  int by = wg % ny;
  long bx = wg / ny;
  long m0 = bx*128 + w*32;
  int  n0 = by*64;
  long ra0 = m0 + r16;      if (ra0 > tokens-1) ra0 = tokens-1;
  long ra1 = m0 + 16 + r16; if (ra1 > tokens-1) ra1 = tokens-1;
  f32x4 acc[2][4] = { { {0,0,0,0},{0,0,0,0},{0,0,0,0},{0,0,0,0} },
                      { {0,0,0,0},{0,0,0,0},{0,0,0,0},{0,0,0,0} } };
  for (int k0 = 0; k0 < K; k0 += 32){
    bf16x8 a0 = *reinterpret_cast<const bf16x8*>(A + ra0*K + k0 + kg*8);
    bf16x8 a1 = *reinterpret_cast<const bf16x8*>(A + ra1*K + k0 + kg*8);
    #pragma unroll
    for (int f=0; f<4; ++f){
      bf16x8 b = *reinterpret_cast<const bf16x8*>(W + (long)(n0 + f*16 + r16)*K + k0 + kg*8);
      acc[0][f] = __builtin_amdgcn_mfma_f32_16x16x32_bf16(a0, b, acc[0][f], 0, 0, 0);
      acc[1][f] = __builtin_amdgcn_mfma_f32_16x16x32_bf16(a1, b, acc[1][f], 0, 0, 0);
    }
  }
  if (EPI == 5){
    float gv[4], bv[4], biasv[4];
    #pragma unroll
    for (int f=0; f<4; ++f){
      gv[f] = lng[f*16+r16]; bv[f] = lnb[f*16+r16];
      biasv[f] = bias ? bias[f*16+r16] : 0.f;
    }
    #pragma unroll
    for (int g2=0; g2<2; ++g2){
      #pragma unroll
      for (int r=0; r<4; ++r){
        long row = m0 + g2*16 + kg*4 + r;
        bool ok = row < tokens;
        long rowc = ok ? row : (tokens-1);
        float v[4]; float s = 0.f, qq = 0.f;
        #pragma unroll
        for (int f=0; f<4; ++f){
          float t = acc[g2][f][r] + biasv[f] + bf2f(resid[rowc*64 + f*16+r16]);
          v[f] = t; s += t; qq += t*t;
        }
        #pragma unroll
        for (int m=1; m<16; m<<=1){ s += __shfl_xor(s,m); qq += __shfl_xor(qq,m); }
        float mean = s*(1.f/64.f);
        float var  = qq*(1.f/64.f) - mean*mean;
        float rstd = rsqrtf(var+EPSV);
        if (ok){
          #pragma unroll
          for (int f=0; f<4; ++f){
            resid[row*64 + f*16+r16] = f2bf(v[f]);
            out1 [row*64 + f*16+r16] = f2bf((v[f]-mean)*rstd*gv[f] + bv[f]);
          }
        }
      }
    }
    return;
  }
  #pragma unroll
  for (int g2=0; g2<2; ++g2){
    #pragma unroll
    for (int f=0; f<4; ++f){
      int col = n0 + f*16 + r16;
      #pragma unroll
      for (int r=0; r<4; ++r){
        long row = m0 + g2*16 + kg*4 + r;
        if (row >= tokens) continue;
        float v = acc[g2][f][r];
        if (EPI == 0){
          if (col < NH) out1[row*NH + col] = f2bf(v);
          else          out2[row*NH + col - NH] = f2bf(siluf(v));
        } else if (EPI == 2){
          v += bias[col];
          v = 0.5f*v*(1.f + erff(v*0.70710678118f));
          out1[row*N + col] = f2bf(v);
        }
      }
    }
  }
}

// ======================= m_out GEMM with fused combine+gate =======================
// A[row,k] = (yf[row,k] + yb[mirror,k]) * zm[row,k]  staged to LDS (k in 2 halves)
// out[row,col] = (A @ W^T)[row,col] * gate[row,col]   (N=128, K=256)
__global__ __launch_bounds__(256) void gemm_mout_fused(
    const __hip_bfloat16* __restrict__ yb,   // [2nb*LL,256]
    const __hip_bfloat16* __restrict__ zm,   // [nb*LL,256]
    const __hip_bfloat16* __restrict__ W,    // [128,256]
    const __hip_bfloat16* __restrict__ gate, // zblk [nb*LL,128]
    __hip_bfloat16* __restrict__ out,        // yo [nb*LL,128]
    int tokens, int nb)
{
  __shared__ __hip_bfloat16 at[128][136];
  int w = threadIdx.x >> 6, lane = threadIdx.x & 63;
  int r16 = lane & 15, kg = lane >> 4;
  int nwg = gridDim.x;
  int orig = blockIdx.x;
  int q = nwg >> 3, r8 = nwg & 7;
  int xcd = orig & 7, off = orig >> 3;
  int wg = (xcd < r8 ? xcd*(q+1) : r8*(q+1) + (xcd-r8)*q) + off;
  long m0 = (long)wg*128;
  int sr  = threadIdx.x >> 1;
  int sc0 = (threadIdx.x & 1) * 64;
  long srow = m0 + sr; if (srow > tokens-1) srow = tokens-1;
  long sl = srow % LL, sb = srow / LL;
  long mrow = ((long)nb + sb)*LL + (LL-1-sl);
  f32x4 acc[2][8];
  #pragma unroll
  for (int g2=0; g2<2; ++g2)
    #pragma unroll
    for (int f=0; f<8; ++f) acc[g2][f] = (f32x4){0,0,0,0};
  #pragma unroll
  for (int kh=0; kh<2; ++kh){
    if (kh) __syncthreads();
    #pragma unroll
    for (int u8=0; u8<8; ++u8){
      int c = sc0 + u8*8;
      int cg = kh*128 + c;
      bf16x8 vf = *reinterpret_cast<const bf16x8*>(yb + srow*256 + cg);
      bf16x8 vb = *reinterpret_cast<const bf16x8*>(yb + mrow*256 + cg);
      bf16x8 zz = *reinterpret_cast<const bf16x8*>(zm + srow*256 + cg);
      bf16x8 cmb;
      #pragma unroll
      for (int k=0;k<8;++k) cmb[k] = f2s((s2f(vf[k]) + s2f(vb[k])) * s2f(zz[k]));
      *reinterpret_cast<bf16x8*>(&at[sr][c]) = cmb;
    }
    __syncthreads();
    #pragma unroll
    for (int ks=0; ks<4; ++ks){
      bf16x8 a0 = *reinterpret_cast<const bf16x8*>(&at[w*32 + r16][ks*32 + kg*8]);
      bf16x8 a1 = *reinterpret_cast<const bf16x8*>(&at[w*32 + 16 + r16][ks*32 + kg*8]);
      #pragma unroll
      for (int f=0; f<8; ++f){
        bf16x8 b = *reinterpret_cast<const bf16x8*>(W + (long)(f*16+r16)*256 + kh*128 + ks*32 + kg*8);
        acc[0][f] = __builtin_amdgcn_mfma_f32_16x16x32_bf16(a0, b, acc[0][f], 0, 0, 0);
        acc[1][f] = __builtin_amdgcn_mfma_f32_16x16x32_bf16(a1, b, acc[1][f], 0, 0, 0);
      }
    }
  }
  #pragma unroll
  for (int g2=0; g2<2; ++g2){
    #pragma unroll
    for (int f=0; f<8; ++f){
      int col = f*16 + r16;
      #pragma unroll
      for (int r=0; r<4; ++r){
        long row = m0 + w*32 + g2*16 + kg*4 + r;
        if (row >= tokens) continue;
        out[row*128 + col] = f2bf(acc[g2][f][r] * bf2f(gate[row*128 + col]));
      }
    }
  }
}

// ======================= depthwise conv3d 3x3x3 SAME + silu =======================
__global__ __launch_bounds__(256) void dwconv3d_kernel(
    const __hip_bfloat16* __restrict__ xs, const float* __restrict__ w,
    const float* __restrict__ bias, __hip_bfloat16* __restrict__ seq, int tokens)
{
  long gid = (long)blockIdx.x*256 + threadIdx.x;
  int c = gid & 127;
  long tok = gid >> 7;
  if (tok >= tokens) return;
  int j  = tok % 11;
  int i2 = (tok/11) % 11;
  int t  = (tok/121) % 30;
  long b = tok/LL;
  const float* wc = w + c*27;
  float acc = bias[c];
  #pragma unroll
  for (int dt=0; dt<3; ++dt){
    int tt = t+dt-1; if (tt<0 || tt>=30) continue;
    #pragma unroll
    for (int di=0; di<3; ++di){
      int ii = i2+di-1; if (ii<0 || ii>=11) continue;
      #pragma unroll
      for (int dj=0; dj<3; ++dj){
        int jj = j+dj-1; if (jj<0 || jj>=11) continue;
        long t2 = (b*30+tt)*121 + ii*11 + jj;
        acc += wc[dt*9+di*3+dj] * bf2f(xs[t2*128 + c]);
      }
    }
  }
  seq[tok*128 + c] = f2bf(siluf(acc));
}

// ======================= mamba_pre + scan pass1 fused (pres in LDS) =======================
__global__ __launch_bounds__(256) void mamba_pre_scan(
    const __hip_bfloat16* __restrict__ xm,
    const float* __restrict__ cw, const float* __restrict__ cbv,
    const __hip_bfloat16* __restrict__ xpw_bf,
    const float* __restrict__ dtw, const float* __restrict__ dtbv,
    const float* __restrict__ Alog,
    __hip_bfloat16* __restrict__ ub,
    float* __restrict__ pre,
    float* __restrict__ hfin, float* __restrict__ sdt,
    int nb)
{
  __shared__ __hip_bfloat16 xcs[64][264];
  __shared__ float pres[64][44];
  int s  = blockIdx.x / NCH;
  int ch = blockIdx.x % NCH;
  int p0 = ch*CLEN;
  int b  = s % nb;
  bool fwd = s < nb;
  int d = threadIdx.x;
  const long basex = (long)b*LL*256 + d;
  const long sLL = (long)s*LL;
  {
    float w0=cw[d*4], w1=cw[d*4+1], w2=cw[d*4+2], w3=cw[d*4+3], cb=cbv[d];
    float p1=0.f, p2=0.f, p3=0.f;
    if (p0-1 >= 0) p1 = bf2f(xm[basex + (long)(fwd ? p0-1 : LL-p0  )*256]);
    if (p0-2 >= 0) p2 = bf2f(xm[basex + (long)(fwd ? p0-2 : LL+1-p0)*256]);
    if (p0-3 >= 0) p3 = bf2f(xm[basex + (long)(fwd ? p0-3 : LL+2-p0)*256]);
    for (int t=0; t<64; ++t){
      int p = p0 + t;
      float xl = 0.f;
      if (p < LL) xl = bf2f(xm[basex + (long)(fwd ? p : LL-1-p)*256]);
      float xc = w3*xl + w2*p1 + w1*p2 + w0*p3 + cb;
      p3=p2; p2=p1; p1=xl;
      __hip_bfloat16 uv = f2bf(siluf(xc));
      xcs[t][d] = uv;
      if (p < LL) ub[(sLL + p)*256 + d] = uv;
    }
  }
  __syncthreads();
  {
    int w = threadIdx.x >> 6, lane = threadIdx.x & 63;
    int r16 = lane & 15, kg = lane >> 4;
    int t0 = w*16;
    f32x4 acc[3] = { {0,0,0,0},{0,0,0,0},{0,0,0,0} };
    for (int k0=0; k0<256; k0+=32){
      bf16x8 a = *reinterpret_cast<const bf16x8*>(&xcs[t0+r16][k0+kg*8]);
      #pragma unroll
      for (int f=0; f<3; ++f){
        bf16x8 bb = *reinterpret_cast<const bf16x8*>(xpw_bf + (f*16+r16)*256 + k0 + kg*8);
        acc[f] = __builtin_amdgcn_mfma_f32_16x16x32_bf16(a, bb, acc[f], 0, 0, 0);
      }
    }
    #pragma unroll
    for (int f=0; f<3; ++f){
      int col = f*16 + r16;
      #pragma unroll
      for (int r=0; r<4; ++r){
        int tl = t0 + kg*4 + r;
        int p = p0 + tl;
        if (col < 40){
          pres[tl][col] = acc[f][r];
          if (p < LL) pre[(sLL + p)*40 + col] = acc[f][r];
        }
      }
    }
  }
  __syncthreads();
  {
    int lim = LL - p0; if (lim > CLEN) lim = CLEN;
    f32x2 a2[8], h[8];
    #pragma unroll
    for (int k=0;k<8;++k){
      a2[k] = (f32x2){ -__expf(Alog[d*16+2*k])*1.44269504f,
                       -__expf(Alog[d*16+2*k+1])*1.44269504f };
      h[k] = (f32x2){0.f, 0.f};
    }
    float dw[8];
    #pragma unroll
    for (int r=0;r<8;++r) dw[r] = dtw[d*8+r];
    float dtb_d = dtbv[d];
    float sacc = 0.f;
    for (int t=0; t<lim; ++t){
      float u = bf2f(xcs[t][d]);
      float4 r0 = *reinterpret_cast<const float4*>(&pres[t][0]);
      float4 r1 = *reinterpret_cast<const float4*>(&pres[t][4]);
      float xacc = dtb_d;
      xacc = fmaf(r0.x,dw[0],fmaf(r0.y,dw[1],fmaf(r0.z,dw[2],fmaf(r0.w,dw[3],xacc))));
      xacc = fmaf(r1.x,dw[4],fmaf(r1.y,dw[5],fmaf(r1.z,dw[6],fmaf(r1.w,dw[7],xacc))));
      float dt = (xacc > 20.f) ? xacc : __logf(1.f + __expf(xacc));
      sacc += dt;
      float4 B0 = *reinterpret_cast<const float4*>(&pres[t][8]);
      float4 B1 = *reinterpret_cast<const float4*>(&pres[t][12]);
      float4 B2 = *reinterpret_cast<const float4*>(&pres[t][16]);
      float4 B3 = *reinterpret_cast<const float4*>(&pres[t][20]);
      float Bv[16] = {B0.x,B0.y,B0.z,B0.w,B1.x,B1.y,B1.z,B1.w,
                      B2.x,B2.y,B2.z,B2.w,B3.x,B3.y,B3.z,B3.w};
      f32x2 dt2  = (f32x2){dt, dt};
      float dtu = dt*u;
      f32x2 dtu2 = (f32x2){dtu, dtu};
      #pragma unroll
      for (int k=0;k<8;++k){
        f32x2 tt = dt2*a2[k];
        f32x2 e = (f32x2){ exp2f(tt.x), exp2f(tt.y) };
        f32x2 bk = (f32x2){ Bv[2*k], Bv[2*k+1] };
        h[k] = __builtin_elementwise_fma(e, h[k], dtu2*bk);
      }
    }
    long hbase = ((long)blockIdx.x*256 + d)*16;
    #pragma unroll
    for (int k=0;k<8;++k){ hfin[hbase+2*k] = h[k].x; hfin[hbase+2*k+1] = h[k].y; }
    sdt[(long)blockIdx.x*256 + d] = sacc;
  }
}

// sequential chunk combine (in-place: hfin becomes hinit)
__global__ __launch_bounds__(256) void scan_comb(
    const float* __restrict__ Alog,
    float* __restrict__ hfin, const float* __restrict__ sdt)
{
  int s = blockIdx.x >> 4, dg = blockIdx.x & 15;
  int d = dg*16 + (threadIdx.x >> 4), n = threadIdx.x & 15;
  float a2 = -__expf(Alog[d*16+n]) * 1.44269504f;
  float h = 0.f;
  for (int ch=0; ch<NCH; ++ch){
    long sc = (long)s*NCH + ch;
    long idx = (sc*256 + d)*16 + n;
    float hf = hfin[idx];
    float sd = sdt[sc*256 + d];
    hfin[idx] = h;
    h = exp2f(a2*sd)*h + hf;
  }
}

// pass2: rescan chunk from hinit; write raw y (+u*D) over ub in-place
__global__ __launch_bounds__(256) void scan_p2(
    __hip_bfloat16* __restrict__ ub,
    const float* __restrict__ pre,
    const float* __restrict__ dtw, const float* __restrict__ dtbv,
    const float* __restrict__ Alog, const float* __restrict__ Dv,
    const float* __restrict__ hinit)
{
  int d = threadIdx.x;
  int sc = blockIdx.x;
  int ch = sc % NCH, s = sc / NCH;
  int l0 = ch*CLEN;
  int lim = LL - l0; if (lim > CLEN) lim = CLEN;
  f32x2 a2[8], h[8];
  long hbase = ((long)sc*256 + d)*16;
  #pragma unroll
  for (int k=0;k<8;++k){
    a2[k] = (f32x2){ -__expf(Alog[d*16+2*k])*1.44269504f,
                     -__expf(Alog[d*16+2*k+1])*1.44269504f };
    h[k] = (f32x2){ hinit[hbase+2*k], hinit[hbase+2*k+1] };
  }
  float dw[8];
  #pragma unroll
  for (int r=0;r<8;++r) dw[r] = dtw[d*8+r];
  float dtb_d = dtbv[d];
  float dpv = Dv[d];
  long tok0 = (long)s*LL + l0;
  long ui = tok0*256 + d;
  long pi = tok0*40;
  for (int l=0; l<lim; ++l){
    float u = bf2f(ub[ui]);
    float4 r0 = *reinterpret_cast<const float4*>(pre+pi);
    float4 r1 = *reinterpret_cast<const float4*>(pre+pi+4);
    float xacc = dtb_d;
    xacc = fmaf(r0.x,dw[0],fmaf(r0.y,dw[1],fmaf(r0.z,dw[2],fmaf(r0.w,dw[3],xacc))));
    xacc = fmaf(r1.x,dw[4],fmaf(r1.y,dw[5],fmaf(r1.z,dw[6],fmaf(r1.w,dw[7],xacc))));
    float dt = (xacc > 20.f) ? xacc : __logf(1.f + __expf(xacc));
    f32x16 B = *reinterpret_cast<const f32x16*>(pre+pi+8);
    f32x16 C = *reinterpret_cast<const f32x16*>(pre+pi+24);
    f32x2 dt2  = (f32x2){dt, dt};
    float dtu = dt*u;
    f32x2 dtu2 = (f32x2){dtu, dtu};
    f32x2 y2 = (f32x2){0.f, 0.f};
    #pragma unroll
    for (int k=0;k<8;++k){
      f32x2 t = dt2*a2[k];
      f32x2 e = (f32x2){ exp2f(t.x), exp2f(t.y) };
      f32x2 bk = (f32x2){ B[2*k], B[2*k+1] };
      f32x2 ck = (f32x2){ C[2*k], C[2*k+1] };
      h[k] = __builtin_elementwise_fma(e, h[k], dtu2*bk);
      y2 = __builtin_elementwise_fma(h[k], ck, y2);
    }
    float y = y2.x + y2.y;
    ub[ui] = f2bf(y + u*dpv);
    ui += 256; pi += 40;
  }
}

// ======================= head: two-stage mean + linear =======================
__global__ __launch_bounds__(256) void head1_kernel(
    const __hip_bfloat16* __restrict__ xb, float* __restrict__ hp)
{
  __shared__ float partial[4][64];
  int b = blockIdx.x / 30, ch = blockIdx.x % 30;
  int d = threadIdx.x & 63, part = threadIdx.x >> 6;
  float acc = 0.f;
  int lend = (ch+1)*121;
  for (int l = ch*121 + part; l < lend; l += 4)
    acc += bf2f(xb[((long)b*LL + l)*64 + d]);
  partial[part][d] = acc;
  __syncthreads();
  if (part == 0)
    hp[(b*30 + ch)*64 + d] = partial[0][d]+partial[1][d]+partial[2][d]+partial[3][d];
}

__global__ __launch_bounds__(64) void head2_kernel(
    const float* __restrict__ hp, const float* __restrict__ hw,
    const float* __restrict__ hb, float* __restrict__ out, int b0)
{
  __shared__ float feat[64];
  int b = blockIdx.x;
  int d = threadIdx.x;
  float acc = 0.f;
  #pragma unroll
  for (int ch=0; ch<30; ++ch) acc += hp[(b*30+ch)*64 + d];
  float f = acc * (1.f/3630.f);
  feat[d] = f;
  out[512 + (b0+b)*64 + d] = f;
  __syncthreads();
  if (d < 16){
    float a2 = hb[d];
    #pragma unroll
    for (int k=0; k<64; ++k) a2 += feat[k]*hw[d*64+k];
    out[(b0+b)*16 + d] = a2;
  }
}

// ======================= launch =======================
extern "C" void kernel_launch(void* const* d_in, const int* in_sizes, int n_in,
                              void* d_out, int out_size, void* d_ws, size_t ws_size,
                              hipStream_t stream)
{
  const float* x        = (const float*)d_in[0];
  const float* sconv_w  = (const float*)d_in[1];
  const float* bn1_g    = (const float*)d_in[2];
  const float* bn1_b    = (const float*)d_in[3];
  const float* bn1_m    = (const float*)d_in[4];
  const float* bn1_v    = (const float*)d_in[5];
  const float* tconv_w  = (const float*)d_in[6];
  const float* bn2_g    = (const float*)d_in[7];
  const float* bn2_b    = (const float*)d_in[8];
  const float* bn2_m    = (const float*)d_in[9];
  const float* bn2_v    = (const float*)d_in[10];
  const float* last_w   = (const float*)d_in[11];
  const float* ln1_g    = (const float*)d_in[12];
  const float* ln1_b    = (const float*)d_in[13];
  const float* in_proj_w= (const float*)d_in[14];
  const float* conv3d_w = (const float*)d_in[15];
  const float* conv3d_b = (const float*)d_in[16];
  const float* m_in_w   = (const float*)d_in[17];
  const float* m_conv_w = (const float*)d_in[18];
  const float* m_conv_b = (const float*)d_in[19];
  const float* m_xproj_w= (const float*)d_in[20];
  const float* m_dtproj_w=(const float*)d_in[21];
  const float* m_dtproj_b=(const float*)d_in[22];
  const float* m_Alog   = (const float*)d_in[23];
  const float* m_D      = (const float*)d_in[24];
  const float* m_out_w  = (const float*)d_in[25];
  const float* out_proj_w=(const float*)d_in[26];
  const float* ln2_g    = (const float*)d_in[27];
  const float* ln2_b    = (const float*)d_in[28];
  const float* fc1_w    = (const float*)d_in[29];
  const float* fc1_b    = (const float*)d_in[30];
  const float* fc2_w    = (const float*)d_in[31];
  const float* fc2_b    = (const float*)d_in[32];
  const float* head_w   = (const float*)d_in[33];
  const float* head_b   = (const float*)d_in[34];

  const size_t WB = 1345536;
  int nb = 1;
  for (int cand = 32; cand >= 1; cand >>= 1){
    size_t TPc = (((size_t)cand*LL + 63)/64)*64;
    size_t S2c = (size_t)2*cand*LL;
    size_t need = WB + TPc*2048 + S2c*672;
    if (need <= ws_size){ nb = cand; break; }
  }
  const size_t TP  = (((size_t)nb*LL + 63)/64)*64;
  const int S2  = 2*nb;
  const size_t S2T = (size_t)S2*LL;
  const int tokens = nb*LL;

  char* ws = (char*)d_ws;
  __hip_bfloat16* wbf   = (__hip_bfloat16*)(ws);
  size_t o = WB;
  __hip_bfloat16* xb    = (__hip_bfloat16*)(ws + o); o += TP*128;
  __hip_bfloat16* hx    = (__hip_bfloat16*)(ws + o); o += TP*128;
  float*          hp    = (float*)hx;
  float*          hfin  = (float*)hx;       // spans hx+xs+seq during scan phase
  __hip_bfloat16* xs    = (__hip_bfloat16*)(ws + o); o += TP*256;
  __hip_bfloat16* seq   = (__hip_bfloat16*)(ws + o); o += TP*256;
  __hip_bfloat16* zblk  = (__hip_bfloat16*)(ws + o); o += TP*256;
  __hip_bfloat16* xm    = (__hip_bfloat16*)(ws + o);
  __hip_bfloat16* yo    = xm;                        o += TP*512;
  __hip_bfloat16* zm    = (__hip_bfloat16*)(ws + o);
  __hip_bfloat16* h2m   = zm;                        o += TP*512;
  float*          pre   = (float*)(ws + o);          o += S2T*160;
  __hip_bfloat16* ybuf  = (__hip_bfloat16*)(ws + o);
  float*          h1s   = (float*)(ws + o);
  float*          h2s   = (float*)(ws + o + (size_t)nb*495616);
  float*          sdtb  = hfin + (size_t)S2*NCH*4096;

  convert_weights<<<2624, 256, 0, stream>>>(in_proj_w, m_in_w, m_out_w, out_proj_w,
                                            fc1_w, fc2_w, m_xproj_w, wbf);

  const int gM2 = (int)((TP + 127)/128);

  for (int b0 = 0; b0 < 32; b0 += nb){
    stem1_kernel<<<nb*484, 256, 0, stream>>>(x, sconv_w, bn1_g, bn1_b, bn1_m, bn1_v, h1s, nb, b0);
    stem2_kernel<<<(nb*116160+255)/256, 256, 0, stream>>>(h1s, tconv_w, bn2_g, bn2_b, bn2_m, bn2_v, h2s, nb);
    stem3_kernel<<<(tokens*64+255)/256, 256, 0, stream>>>(h2s, last_w, ln1_g, ln1_b, xb, hx, tokens);

    for (int i = 0; i < 4; ++i){
      gemm_bf16<0><<<gM2*4, 256, 0, stream>>>(hx, wbf + i*16384, 64, 256, 128, 4, tokens,
                                              xs, zblk, nullptr, nullptr, nullptr, nullptr, nullptr);
      dwconv3d_kernel<<<(tokens*128+255)/256, 256, 0, stream>>>(xs, conv3d_w + i*3456, conv3d_b + i*128, seq, tokens);
      gemm_bf16<0><<<gM2*8, 256, 0, stream>>>(seq, wbf + 65536 + i*65536, 128, 512, 256, 8, tokens,
                                              xm, zm, nullptr, nullptr, nullptr, nullptr, nullptr);
      mamba_pre_scan<<<S2*NCH, 256, 0, stream>>>(xm, m_conv_w + i*1024, m_conv_b + i*256,
                                                 wbf + 622592 + i*12288,
                                                 m_dtproj_w + i*2048, m_dtproj_b + i*256,
                                                 m_Alog + i*4096,
                                                 ybuf, pre, hfin, sdtb, nb);
      scan_comb<<<S2*16, 256, 0, stream>>>(m_Alog + i*4096, hfin, sdtb);
      scan_p2<<<S2*NCH, 256, 0, stream>>>(ybuf, pre, m_dtproj_w + i*2048, m_dtproj_b + i*256,
                                          m_Alog + i*4096, m_D + i*256, hfin);
      gemm_mout_fused<<<gM2, 256, 0, stream>>>(ybuf, zm, wbf + 327680 + i*32768, zblk, yo,
                                               tokens, nb);
      gemm_bf16<5><<<gM2, 256, 0, stream>>>(yo, wbf + 458752 + i*8192, 128, 64, 0, 1, tokens,
                                            hx, nullptr, nullptr, nullptr, xb,
                                            ln2_g + i*64, ln2_b + i*64);
      gemm_bf16<2><<<gM2*4, 256, 0, stream>>>(hx, wbf + 491520 + i*16384, 64, 256, 0, 4, tokens,
                                              h2m, nullptr, fc1_b + i*256, nullptr, nullptr, nullptr, nullptr);
      int inext = (i < 3) ? i+1 : 3;
      gemm_bf16<5><<<gM2, 256, 0, stream>>>(h2m, wbf + 557056 + i*16384, 256, 64, 0, 1, tokens,
                                            hx, nullptr, fc2_b + i*64, nullptr, xb,
                                            ln1_g + inext*64, ln1_b + inext*64);
    }
    head1_kernel<<<nb*30, 256, 0, stream>>>(xb, hp);
    head2_kernel<<<nb, 64, 0, stream>>>(hp, head_w, head_b, (float*)d_out, b0);
  }
}

// Round 13
// 6166.385 us; speedup vs baseline: 1.0788x; 1.0788x over previous
//
#include <hip/hip_runtime.h>
#include <hip/hip_bf16.h>
#include <hip/hip_fp16.h>

#define LL    3630
#define EPSV  1e-5f
#define NCH   57      // scan chunks (64-token, matches mamba_pre blocks)
#define CLEN  64

typedef short bf16x8 __attribute__((ext_vector_type(8)));
typedef float f32x4  __attribute__((ext_vector_type(4)));
typedef float f32x2  __attribute__((ext_vector_type(2)));
typedef float f32x16 __attribute__((ext_vector_type(16)));

__device__ __forceinline__ float bf2f(__hip_bfloat16 x){ return __bfloat162float(x); }
__device__ __forceinline__ __hip_bfloat16 f2bf(float x){ return __float2bfloat16(x); }
__device__ __forceinline__ float siluf(float x){ return x / (1.f + __expf(-x)); }
__device__ __forceinline__ float s2f(short s){ __hip_bfloat16 t = __builtin_bit_cast(__hip_bfloat16, s); return __bfloat162float(t); }
__device__ __forceinline__ short f2s(float x){ __hip_bfloat16 t = __float2bfloat16(x); return __builtin_bit_cast(short, t); }

// ======================= weight f32 -> bf16 =======================
__global__ __launch_bounds__(256) void convert_weights(
    const float* __restrict__ s0, const float* __restrict__ s1,
    const float* __restrict__ s2, const float* __restrict__ s3,
    const float* __restrict__ s4, const float* __restrict__ s5,
    const float* __restrict__ s6,
    __hip_bfloat16* __restrict__ dst)
{
  int gid = blockIdx.x*256 + threadIdx.x;
  float v;
  if      (gid <  65536) v = s0[gid];
  else if (gid < 327680) v = s1[gid-65536];
  else if (gid < 458752) v = s2[gid-327680];
  else if (gid < 491520) v = s3[gid-458752];
  else if (gid < 557056) v = s4[gid-491520];
  else if (gid < 622592) v = s5[gid-557056];
  else if (gid < 671744){
    int rel = gid - 622592;
    int layer = rel / 12288;
    int rr  = (rel % 12288) / 256;
    int ccol= rel & 255;
    v = (rr < 40) ? s6[layer*10240 + rr*256 + ccol] : 0.f;
  }
  else return;
  dst[gid] = f2bf(v);
}

// ======================= stem =======================
__global__ __launch_bounds__(256) void stem1_kernel(
    const float* __restrict__ x, const float* __restrict__ w,
    const float* __restrict__ g, const float* __restrict__ bb,
    const float* __restrict__ mm, const float* __restrict__ vv,
    float* __restrict__ out, int nb, int b0)
{
  int idx = blockIdx.x*256 + threadIdx.x;
  if (idx >= nb*123904) return;
  int j = idx % 11;
  int i = (idx/11) % 11;
  int t = (idx/121) % 32;
  int c = (idx/(121*32)) % 32;
  int b = idx/(121*32*32);
  const float* xp = x + ((b0+b)*32 + t)*169;
  const float* wp = w + c*9;
  float acc = 0.f;
  #pragma unroll
  for (int di=0; di<3; ++di)
    #pragma unroll
    for (int dj=0; dj<3; ++dj)
      acc += xp[(i+di)*13 + (j+dj)] * wp[di*3+dj];
  float s = g[c]*rsqrtf(vv[c]+EPSV);
  acc = acc*s + (bb[c]-mm[c]*s);
  out[idx] = fmaxf(acc, 0.f);
}

__global__ __launch_bounds__(256) void stem2_kernel(
    const float* __restrict__ h1, const float* __restrict__ w,
    const float* __restrict__ g, const float* __restrict__ bb,
    const float* __restrict__ mm, const float* __restrict__ vv,
    float* __restrict__ out, int nb)
{
  int idx = blockIdx.x*256 + threadIdx.x;
  if (idx >= nb*116160) return;
  int ij = idx % 121;
  int t  = (idx/121) % 30;
  int c  = (idx/(121*30)) % 32;
  int b  = idx/(121*30*32);
  const float* hp = h1 + ((b*32+c)*32)*121 + ij;
  const float* wp = w + c*3;
  float acc = 0.f;
  #pragma unroll
  for (int k=0;k<3;++k) acc += hp[(t+k)*121] * wp[k];
  float s = g[c]*rsqrtf(vv[c]+EPSV);
  acc = acc*s + (bb[c]-mm[c]*s);
  out[idx] = fmaxf(acc, 0.f);
}

// stem3 + fused LayerNorm (wave = one token, lane = channel)
__global__ __launch_bounds__(256) void stem3_kernel(
    const float* __restrict__ h2, const float* __restrict__ w,
    const float* __restrict__ lng, const float* __restrict__ lnb,
    __hip_bfloat16* __restrict__ xb, __hip_bfloat16* __restrict__ hx, int tokens)
{
  int gid = blockIdx.x*256 + threadIdx.x;
  int cc = gid & 63;
  int tok = gid >> 6;
  if (tok >= tokens) return;
  int ij = tok % 121;
  int t  = (tok/121) % 30;
  int b  = tok/LL;
  const float* hp = h2 + ((long)b*32)*30*121 + t*121 + ij;
  const float* wp = w + cc*32;
  float acc = 0.f;
  #pragma unroll
  for (int ci=0; ci<32; ++ci) acc += hp[ci*3630] * wp[ci];
  xb[(long)tok*64+cc] = f2bf(acc);
  float s = acc, q = acc*acc;
  #pragma unroll
  for (int m=1; m<64; m<<=1){ s += __shfl_xor(s,m); q += __shfl_xor(q,m); }
  float mean = s*(1.f/64.f);
  float var  = q*(1.f/64.f) - mean*mean;
  hx[(long)tok*64+cc] = f2bf((acc-mean)*rsqrtf(var+EPSV)*lng[cc] + lnb[cc]);
}

// ======================= bf16 MFMA GEMM: 128-row blocks + XCD-chunk swizzle =======================
template<int EPI>
__global__ __launch_bounds__(256) void gemm_bf16(
    const __hip_bfloat16* __restrict__ A, const __hip_bfloat16* __restrict__ W,
    int K, int N, int NH, int ny, int tokens,
    __hip_bfloat16* __restrict__ out1, __hip_bfloat16* __restrict__ out2,
    const float* __restrict__ bias, const __hip_bfloat16* __restrict__ gate,
    __hip_bfloat16* __restrict__ resid,
    const float* __restrict__ lng, const float* __restrict__ lnb)
{
  int w   = threadIdx.x >> 6;
  int lane= threadIdx.x & 63;
  int r16 = lane & 15;
  int kg  = lane >> 4;          // 0..3
  int nwg = gridDim.x;
  int orig = blockIdx.x;
  int q = nwg >> 3, r8 = nwg & 7;
  int xcd = orig & 7, off = orig >> 3;
  int wg = (xcd < r8 ? xcd*(q+1) : r8*(q+1) + (xcd-r8)*q) + off;
  int by = wg % ny;
  long bx = wg / ny;
  long m0 = bx*128 + w*32;
  int  n0 = by*64;
  long ra0 = m0 + r16;      if (ra0 > tokens-1) ra0 = tokens-1;
  long ra1 = m0 + 16 + r16; if (ra1 > tokens-1) ra1 = tokens-1;
  f32x4 acc[2][4] = { { {0,0,0,0},{0,0,0,0},{0,0,0,0},{0,0,0,0} },
                      { {0,0,0,0},{0,0,0,0},{0,0,0,0},{0,0,0,0} } };
  for (int k0 = 0; k0 < K; k0 += 32){
    bf16x8 a0 = *reinterpret_cast<const bf16x8*>(A + ra0*K + k0 + kg*8);
    bf16x8 a1 = *reinterpret_cast<const bf16x8*>(A + ra1*K + k0 + kg*8);
    #pragma unroll
    for (int f=0; f<4; ++f){
      bf16x8 b = *reinterpret_cast<const bf16x8*>(W + (long)(n0 + f*16 + r16)*K + k0 + kg*8);
      acc[0][f] = __builtin_amdgcn_mfma_f32_16x16x32_bf16(a0, b, acc[0][f], 0, 0, 0);
      acc[1][f] = __builtin_amdgcn_mfma_f32_16x16x32_bf16(a1, b, acc[1][f], 0, 0, 0);
    }
  }
  if (EPI == 5){
    float gv[4], bv[4], biasv[4];
    #pragma unroll
    for (int f=0; f<4; ++f){
      gv[f] = lng[f*16+r16]; bv[f] = lnb[f*16+r16];
      biasv[f] = bias ? bias[f*16+r16] : 0.f;
    }
    #pragma unroll
    for (int g2=0; g2<2; ++g2){
      #pragma unroll
      for (int r=0; r<4; ++r){
        long row = m0 + g2*16 + kg*4 + r;
        bool ok = row < tokens;
        long rowc = ok ? row : (tokens-1);
        float v[4]; float s = 0.f, qq = 0.f;
        #pragma unroll
        for (int f=0; f<4; ++f){
          float t = acc[g2][f][r] + biasv[f] + bf2f(resid[rowc*64 + f*16+r16]);
          v[f] = t; s += t; qq += t*t;
        }
        #pragma unroll
        for (int m=1; m<16; m<<=1){ s += __shfl_xor(s,m); qq += __shfl_xor(qq,m); }
        float mean = s*(1.f/64.f);
        float var  = qq*(1.f/64.f) - mean*mean;
        float rstd = rsqrtf(var+EPSV);
        if (ok){
          #pragma unroll
          for (int f=0; f<4; ++f){
            resid[row*64 + f*16+r16] = f2bf(v[f]);
            out1 [row*64 + f*16+r16] = f2bf((v[f]-mean)*rstd*gv[f] + bv[f]);
          }
        }
      }
    }
    return;
  }
  #pragma unroll
  for (int g2=0; g2<2; ++g2){
    #pragma unroll
    for (int f=0; f<4; ++f){
      int col = n0 + f*16 + r16;
      #pragma unroll
      for (int r=0; r<4; ++r){
        long row = m0 + g2*16 + kg*4 + r;
        if (row >= tokens) continue;
        float v = acc[g2][f][r];
        if (EPI == 0){
          if (col < NH) out1[row*NH + col] = f2bf(v);
          else          out2[row*NH + col - NH] = f2bf(siluf(v));
        } else if (EPI == 2){
          v += bias[col];
          v = 0.5f*v*(1.f + erff(v*0.70710678118f));
          out1[row*N + col] = f2bf(v);
        } else {
          out1[row*N + col] = f2bf(v * bf2f(gate[row*N + col]));
        }
      }
    }
  }
}

// ======================= depthwise conv3d 3x3x3 SAME + silu =======================
__global__ __launch_bounds__(256) void dwconv3d_kernel(
    const __hip_bfloat16* __restrict__ xs, const float* __restrict__ w,
    const float* __restrict__ bias, __hip_bfloat16* __restrict__ seq, int tokens)
{
  long gid = (long)blockIdx.x*256 + threadIdx.x;
  int c = gid & 127;
  long tok = gid >> 7;
  if (tok >= tokens) return;
  int j  = tok % 11;
  int i2 = (tok/11) % 11;
  int t  = (tok/121) % 30;
  long b = tok/LL;
  const float* wc = w + c*27;
  float acc = bias[c];
  #pragma unroll
  for (int dt=0; dt<3; ++dt){
    int tt = t+dt-1; if (tt<0 || tt>=30) continue;
    #pragma unroll
    for (int di=0; di<3; ++di){
      int ii = i2+di-1; if (ii<0 || ii>=11) continue;
      #pragma unroll
      for (int dj=0; dj<3; ++dj){
        int jj = j+dj-1; if (jj<0 || jj>=11) continue;
        long t2 = (b*30+tt)*121 + ii*11 + jj;
        acc += wc[dt*9+di*3+dj] * bf2f(xs[t2*128 + c]);
      }
    }
  }
  seq[tok*128 + c] = f2bf(siluf(acc));
}

// ======================= mamba_pre + scan pass1 fused (pres in LDS) =======================
__global__ __launch_bounds__(256) void mamba_pre_scan(
    const __hip_bfloat16* __restrict__ xm,
    const float* __restrict__ cw, const float* __restrict__ cbv,
    const __hip_bfloat16* __restrict__ xpw_bf,
    const float* __restrict__ dtw, const float* __restrict__ dtbv,
    const float* __restrict__ Alog,
    __hip_bfloat16* __restrict__ ub,
    float* __restrict__ pre,
    float* __restrict__ hfin, float* __restrict__ sdt,
    int nb)
{
  __shared__ __hip_bfloat16 xcs[64][264];
  __shared__ float pres[64][44];
  int s  = blockIdx.x / NCH;
  int ch = blockIdx.x % NCH;
  int p0 = ch*CLEN;
  int b  = s % nb;
  bool fwd = s < nb;
  int d = threadIdx.x;
  const long basex = (long)b*LL*256 + d;
  const long sLL = (long)s*LL;
  {
    float w0=cw[d*4], w1=cw[d*4+1], w2=cw[d*4+2], w3=cw[d*4+3], cb=cbv[d];
    float p1=0.f, p2=0.f, p3=0.f;
    if (p0-1 >= 0) p1 = bf2f(xm[basex + (long)(fwd ? p0-1 : LL-p0  )*256]);
    if (p0-2 >= 0) p2 = bf2f(xm[basex + (long)(fwd ? p0-2 : LL+1-p0)*256]);
    if (p0-3 >= 0) p3 = bf2f(xm[basex + (long)(fwd ? p0-3 : LL+2-p0)*256]);
    for (int t=0; t<64; ++t){
      int p = p0 + t;
      float xl = 0.f;
      if (p < LL) xl = bf2f(xm[basex + (long)(fwd ? p : LL-1-p)*256]);
      float xc = w3*xl + w2*p1 + w1*p2 + w0*p3 + cb;
      p3=p2; p2=p1; p1=xl;
      __hip_bfloat16 uv = f2bf(siluf(xc));
      xcs[t][d] = uv;
      if (p < LL) ub[(sLL + p)*256 + d] = uv;
    }
  }
  __syncthreads();
  {
    int w = threadIdx.x >> 6, lane = threadIdx.x & 63;
    int r16 = lane & 15, kg = lane >> 4;
    int t0 = w*16;
    f32x4 acc[3] = { {0,0,0,0},{0,0,0,0},{0,0,0,0} };
    for (int k0=0; k0<256; k0+=32){
      bf16x8 a = *reinterpret_cast<const bf16x8*>(&xcs[t0+r16][k0+kg*8]);
      #pragma unroll
      for (int f=0; f<3; ++f){
        bf16x8 bb = *reinterpret_cast<const bf16x8*>(xpw_bf + (f*16+r16)*256 + k0 + kg*8);
        acc[f] = __builtin_amdgcn_mfma_f32_16x16x32_bf16(a, bb, acc[f], 0, 0, 0);
      }
    }
    #pragma unroll
    for (int f=0; f<3; ++f){
      int col = f*16 + r16;
      #pragma unroll
      for (int r=0; r<4; ++r){
        int tl = t0 + kg*4 + r;
        int p = p0 + tl;
        if (col < 40){
          pres[tl][col] = acc[f][r];
          if (p < LL) pre[(sLL + p)*40 + col] = acc[f][r];
        }
      }
    }
  }
  __syncthreads();
  {
    int lim = LL - p0; if (lim > CLEN) lim = CLEN;
    f32x2 a2[8], h[8];
    #pragma unroll
    for (int k=0;k<8;++k){
      a2[k] = (f32x2){ -__expf(Alog[d*16+2*k])*1.44269504f,
                       -__expf(Alog[d*16+2*k+1])*1.44269504f };
      h[k] = (f32x2){0.f, 0.f};
    }
    float dw[8];
    #pragma unroll
    for (int r=0;r<8;++r) dw[r] = dtw[d*8+r];
    float dtb_d = dtbv[d];
    float sacc = 0.f;
    for (int t=0; t<lim; ++t){
      float u = bf2f(xcs[t][d]);
      float4 r0 = *reinterpret_cast<const float4*>(&pres[t][0]);
      float4 r1 = *reinterpret_cast<const float4*>(&pres[t][4]);
      float xacc = dtb_d;
      xacc = fmaf(r0.x,dw[0],fmaf(r0.y,dw[1],fmaf(r0.z,dw[2],fmaf(r0.w,dw[3],xacc))));
      xacc = fmaf(r1.x,dw[4],fmaf(r1.y,dw[5],fmaf(r1.z,dw[6],fmaf(r1.w,dw[7],xacc))));
      float dt = (xacc > 20.f) ? xacc : __logf(1.f + __expf(xacc));
      sacc += dt;
      float4 B0 = *reinterpret_cast<const float4*>(&pres[t][8]);
      float4 B1 = *reinterpret_cast<const float4*>(&pres[t][12]);
      float4 B2 = *reinterpret_cast<const float4*>(&pres[t][16]);
      float4 B3 = *reinterpret_cast<const float4*>(&pres[t][20]);
      float Bv[16] = {B0.x,B0.y,B0.z,B0.w,B1.x,B1.y,B1.z,B1.w,
                      B2.x,B2.y,B2.z,B2.w,B3.x,B3.y,B3.z,B3.w};
      f32x2 dt2  = (f32x2){dt, dt};
      float dtu = dt*u;
      f32x2 dtu2 = (f32x2){dtu, dtu};
      #pragma unroll
      for (int k=0;k<8;++k){
        f32x2 tt = dt2*a2[k];
        f32x2 e = (f32x2){ exp2f(tt.x), exp2f(tt.y) };
        f32x2 bk = (f32x2){ Bv[2*k], Bv[2*k+1] };
        h[k] = __builtin_elementwise_fma(e, h[k], dtu2*bk);
      }
    }
    long hbase = ((long)blockIdx.x*256 + d)*16;
    #pragma unroll
    for (int k=0;k<8;++k){ hfin[hbase+2*k] = h[k].x; hfin[hbase+2*k+1] = h[k].y; }
    sdt[(long)blockIdx.x*256 + d] = sacc;
  }
}

// sequential chunk combine (in-place: hfin becomes hinit)
__global__ __launch_bounds__(256) void scan_comb(
    const float* __restrict__ Alog,
    float* __restrict__ hfin, const float* __restrict__ sdt)
{
  int s = blockIdx.x >> 4, dg = blockIdx.x & 15;
  int d = dg*16 + (threadIdx.x >> 4), n = threadIdx.x & 15;
  float a2 = -__expf(Alog[d*16+n]) * 1.44269504f;
  float h = 0.f;
  for (int ch=0; ch<NCH; ++ch){
    long sc = (long)s*NCH + ch;
    long idx = (sc*256 + d)*16 + n;
    float hf = hfin[idx];
    float sd = sdt[sc*256 + d];
    hfin[idx] = h;
    h = exp2f(a2*sd)*h + hf;
  }
}

// pass2: rescan chunk from hinit; write raw y (+u*D) over ub in-place
__global__ __launch_bounds__(256) void scan_p2(
    __hip_bfloat16* __restrict__ ub,
    const float* __restrict__ pre,
    const float* __restrict__ dtw, const float* __restrict__ dtbv,
    const float* __restrict__ Alog, const float* __restrict__ Dv,
    const float* __restrict__ hinit)
{
  int d = threadIdx.x;
  int sc = blockIdx.x;
  int ch = sc % NCH, s = sc / NCH;
  int l0 = ch*CLEN;
  int lim = LL - l0; if (lim > CLEN) lim = CLEN;
  f32x2 a2[8], h[8];
  long hbase = ((long)sc*256 + d)*16;
  #pragma unroll
  for (int k=0;k<8;++k){
    a2[k] = (f32x2){ -__expf(Alog[d*16+2*k])*1.44269504f,
                     -__expf(Alog[d*16+2*k+1])*1.44269504f };
    h[k] = (f32x2){ hinit[hbase+2*k], hinit[hbase+2*k+1] };
  }
  float dw[8];
  #pragma unroll
  for (int r=0;r<8;++r) dw[r] = dtw[d*8+r];
  float dtb_d = dtbv[d];
  float dpv = Dv[d];
  long tok0 = (long)s*LL + l0;
  long ui = tok0*256 + d;
  long pi = tok0*40;
  #pragma unroll 2
  for (int l=0; l<lim; ++l){
    float u = bf2f(ub[ui]);
    float4 r0 = *reinterpret_cast<const float4*>(pre+pi);
    float4 r1 = *reinterpret_cast<const float4*>(pre+pi+4);
    float xacc = dtb_d;
    xacc = fmaf(r0.x,dw[0],fmaf(r0.y,dw[1],fmaf(r0.z,dw[2],fmaf(r0.w,dw[3],xacc))));
    xacc = fmaf(r1.x,dw[4],fmaf(r1.y,dw[5],fmaf(r1.z,dw[6],fmaf(r1.w,dw[7],xacc))));
    float dt = (xacc > 20.f) ? xacc : __logf(1.f + __expf(xacc));
    f32x16 B = *reinterpret_cast<const f32x16*>(pre+pi+8);
    f32x16 C = *reinterpret_cast<const f32x16*>(pre+pi+24);
    f32x2 dt2  = (f32x2){dt, dt};
    float dtu = dt*u;
    f32x2 dtu2 = (f32x2){dtu, dtu};
    f32x2 y2 = (f32x2){0.f, 0.f};
    #pragma unroll
    for (int k=0;k<8;++k){
      f32x2 t = dt2*a2[k];
      f32x2 e = (f32x2){ exp2f(t.x), exp2f(t.y) };
      f32x2 bk = (f32x2){ B[2*k], B[2*k+1] };
      f32x2 ck = (f32x2){ C[2*k], C[2*k+1] };
      h[k] = __builtin_elementwise_fma(e, h[k], dtu2*bk);
      y2 = __builtin_elementwise_fma(h[k], ck, y2);
    }
    float y = y2.x + y2.y;
    ub[ui] = f2bf(y + u*dpv);
    ui += 256; pi += 40;
  }
}

// ======================= combine fwd/bwd + zm gate (bf16x8 vectorized) =======================
__global__ __launch_bounds__(256) void combine_kernel(
    const __hip_bfloat16* __restrict__ yb, const __hip_bfloat16* __restrict__ zm,
    __hip_bfloat16* __restrict__ ycomb, int tokens, int nb)
{
  long gid = (long)blockIdx.x*256 + threadIdx.x;   // one per 8 channels
  long tok = gid >> 5;
  if (tok >= tokens) return;
  int c8 = (gid & 31) * 8;
  long l = tok % LL, b = tok / LL;
  bf16x8 vf = *reinterpret_cast<const bf16x8*>(yb + ( b*LL + l)*256 + c8);
  bf16x8 vb = *reinterpret_cast<const bf16x8*>(yb + ((nb+b)*LL + (LL-1-l))*256 + c8);
  bf16x8 zz = *reinterpret_cast<const bf16x8*>(zm + tok*256 + c8);
  bf16x8 out;
  #pragma unroll
  for (int k=0;k<8;++k){
    float r = (s2f(vf[k]) + s2f(vb[k])) * s2f(zz[k]);
    out[k] = f2s(r);
  }
  *reinterpret_cast<bf16x8*>(ycomb + tok*256 + c8) = out;
}

// ======================= head: two-stage mean + linear =======================
__global__ __launch_bounds__(256) void head1_kernel(
    const __hip_bfloat16* __restrict__ xb, float* __restrict__ hp)
{
  __shared__ float partial[4][64];
  int b = blockIdx.x / 30, ch = blockIdx.x % 30;
  int d = threadIdx.x & 63, part = threadIdx.x >> 6;
  float acc = 0.f;
  int lend = (ch+1)*121;
  for (int l = ch*121 + part; l < lend; l += 4)
    acc += bf2f(xb[((long)b*LL + l)*64 + d]);
  partial[part][d] = acc;
  __syncthreads();
  if (part == 0)
    hp[(b*30 + ch)*64 + d] = partial[0][d]+partial[1][d]+partial[2][d]+partial[3][d];
}

__global__ __launch_bounds__(64) void head2_kernel(
    const float* __restrict__ hp, const float* __restrict__ hw,
    const float* __restrict__ hb, float* __restrict__ out, int b0)
{
  __shared__ float feat[64];
  int b = blockIdx.x;
  int d = threadIdx.x;
  float acc = 0.f;
  #pragma unroll
  for (int ch=0; ch<30; ++ch) acc += hp[(b*30+ch)*64 + d];
  float f = acc * (1.f/3630.f);
  feat[d] = f;
  out[512 + (b0+b)*64 + d] = f;
  __syncthreads();
  if (d < 16){
    float a2 = hb[d];
    #pragma unroll
    for (int k=0; k<64; ++k) a2 += feat[k]*hw[d*64+k];
    out[(b0+b)*16 + d] = a2;
  }
}

// ======================= launch =======================
extern "C" void kernel_launch(void* const* d_in, const int* in_sizes, int n_in,
                              void* d_out, int out_size, void* d_ws, size_t ws_size,
                              hipStream_t stream)
{
  const float* x        = (const float*)d_in[0];
  const float* sconv_w  = (const float*)d_in[1];
  const float* bn1_g    = (const float*)d_in[2];
  const float* bn1_b    = (const float*)d_in[3];
  const float* bn1_m    = (const float*)d_in[4];
  const float* bn1_v    = (const float*)d_in[5];
  const float* tconv_w  = (const float*)d_in[6];
  const float* bn2_g    = (const float*)d_in[7];
  const float* bn2_b    = (const float*)d_in[8];
  const float* bn2_m    = (const float*)d_in[9];
  const float* bn2_v    = (const float*)d_in[10];
  const float* last_w   = (const float*)d_in[11];
  const float* ln1_g    = (const float*)d_in[12];
  const float* ln1_b    = (const float*)d_in[13];
  const float* in_proj_w= (const float*)d_in[14];
  const float* conv3d_w = (const float*)d_in[15];
  const float* conv3d_b = (const float*)d_in[16];
  const float* m_in_w   = (const float*)d_in[17];
  const float* m_conv_w = (const float*)d_in[18];
  const float* m_conv_b = (const float*)d_in[19];
  const float* m_xproj_w= (const float*)d_in[20];
  const float* m_dtproj_w=(const float*)d_in[21];
  const float* m_dtproj_b=(const float*)d_in[22];
  const float* m_Alog   = (const float*)d_in[23];
  const float* m_D      = (const float*)d_in[24];
  const float* m_out_w  = (const float*)d_in[25];
  const float* out_proj_w=(const float*)d_in[26];
  const float* ln2_g    = (const float*)d_in[27];
  const float* ln2_b    = (const float*)d_in[28];
  const float* fc1_w    = (const float*)d_in[29];
  const float* fc1_b    = (const float*)d_in[30];
  const float* fc2_w    = (const float*)d_in[31];
  const float* fc2_b    = (const float*)d_in[32];
  const float* head_w   = (const float*)d_in[33];
  const float* head_b   = (const float*)d_in[34];

  const size_t WB = 1345536;
  int nb = 1;
  for (int cand = 32; cand >= 1; cand >>= 1){
    size_t TPc = (((size_t)cand*LL + 63)/64)*64;
    size_t S2c = (size_t)2*cand*LL;
    size_t need = WB + TPc*2048 + S2c*672;
    if (need <= ws_size){ nb = cand; break; }
  }
  const size_t TP  = (((size_t)nb*LL + 63)/64)*64;
  const int S2  = 2*nb;
  const size_t S2T = (size_t)S2*LL;
  const int tokens = nb*LL;

  char* ws = (char*)d_ws;
  __hip_bfloat16* wbf   = (__hip_bfloat16*)(ws);
  size_t o = WB;
  __hip_bfloat16* xb    = (__hip_bfloat16*)(ws + o); o += TP*128;
  __hip_bfloat16* hx    = (__hip_bfloat16*)(ws + o); o += TP*128;
  float*          hp    = (float*)hx;
  float*          hfin  = (float*)hx;       // spans hx+xs+seq during scan phase
  __hip_bfloat16* xs    = (__hip_bfloat16*)(ws + o); o += TP*256;
  __hip_bfloat16* seq   = (__hip_bfloat16*)(ws + o); o += TP*256;
  __hip_bfloat16* ycomb = xs;
  __hip_bfloat16* zblk  = (__hip_bfloat16*)(ws + o); o += TP*256;
  __hip_bfloat16* xm    = (__hip_bfloat16*)(ws + o);
  __hip_bfloat16* yo    = xm;                        o += TP*512;
  __hip_bfloat16* zm    = (__hip_bfloat16*)(ws + o);
  __hip_bfloat16* h2m   = zm;                        o += TP*512;
  float*          pre   = (float*)(ws + o);          o += S2T*160;
  __hip_bfloat16* ybuf  = (__hip_bfloat16*)(ws + o);
  float*          h1s   = (float*)(ws + o);
  float*          h2s   = (float*)(ws + o + (size_t)nb*495616);
  float*          sdtb  = hfin + (size_t)S2*NCH*4096;

  convert_weights<<<2624, 256, 0, stream>>>(in_proj_w, m_in_w, m_out_w, out_proj_w,
                                            fc1_w, fc2_w, m_xproj_w, wbf);

  const int gM2 = (int)((TP + 127)/128);

  for (int b0 = 0; b0 < 32; b0 += nb){
    stem1_kernel<<<nb*484, 256, 0, stream>>>(x, sconv_w, bn1_g, bn1_b, bn1_m, bn1_v, h1s, nb, b0);
    stem2_kernel<<<(nb*116160+255)/256, 256, 0, stream>>>(h1s, tconv_w, bn2_g, bn2_b, bn2_m, bn2_v, h2s, nb);
    stem3_kernel<<<(tokens*64+255)/256, 256, 0, stream>>>(h2s, last_w, ln1_g, ln1_b, xb, hx, tokens);

    for (int i = 0; i < 4; ++i){
      gemm_bf16<0><<<gM2*4, 256, 0, stream>>>(hx, wbf + i*16384, 64, 256, 128, 4, tokens,
                                              xs, zblk, nullptr, nullptr, nullptr, nullptr, nullptr);
      dwconv3d_kernel<<<(tokens*128+255)/256, 256, 0, stream>>>(xs, conv3d_w + i*3456, conv3d_b + i*128, seq, tokens);
      gemm_bf16<0><<<gM2*8, 256, 0, stream>>>(seq, wbf + 65536 + i*65536, 128, 512, 256, 8, tokens,
                                              xm, zm, nullptr, nullptr, nullptr, nullptr, nullptr);
      mamba_pre_scan<<<S2*NCH, 256, 0, stream>>>(xm, m_conv_w + i*1024, m_conv_b + i*256,
                                                 wbf + 622592 + i*12288,
                                                 m_dtproj_w + i*2048, m_dtproj_b + i*256,
                                                 m_Alog + i*4096,
                                                 ybuf, pre, hfin, sdtb, nb);
      scan_comb<<<S2*16, 256, 0, stream>>>(m_Alog + i*4096, hfin, sdtb);
      scan_p2<<<S2*NCH, 256, 0, stream>>>(ybuf, pre, m_dtproj_w + i*2048, m_dtproj_b + i*256,
                                          m_Alog + i*4096, m_D + i*256, hfin);
      combine_kernel<<<(tokens*32+255)/256, 256, 0, stream>>>(ybuf, zm, ycomb, tokens, nb);
      gemm_bf16<4><<<gM2*2, 256, 0, stream>>>(ycomb, wbf + 327680 + i*32768, 256, 128, 0, 2, tokens,
                                              yo, nullptr, nullptr, zblk, nullptr, nullptr, nullptr);
      gemm_bf16<5><<<gM2, 256, 0, stream>>>(yo, wbf + 458752 + i*8192, 128, 64, 0, 1, tokens,
                                            hx, nullptr, nullptr, nullptr, xb,
                                            ln2_g + i*64, ln2_b + i*64);
      gemm_bf16<2><<<gM2*4, 256, 0, stream>>>(hx, wbf + 491520 + i*16384, 64, 256, 0, 4, tokens,
                                              h2m, nullptr, fc1_b + i*256, nullptr, nullptr, nullptr, nullptr);
      int inext = (i < 3) ? i+1 : 3;
      gemm_bf16<5><<<gM2, 256, 0, stream>>>(h2m, wbf + 557056 + i*16384, 256, 64, 0, 1, tokens,
                                            hx, nullptr, fc2_b + i*64, nullptr, xb,
                                            ln1_g + inext*64, ln1_b + inext*64);
    }
    head1_kernel<<<nb*30, 256, 0, stream>>>(xb, hp);
    head2_kernel<<<nb, 64, 0, stream>>>(hp, head_w, head_b, (float*)d_out, b0);
  }
}

// Round 14
// 6096.668 us; speedup vs baseline: 1.0911x; 1.0114x over previous
//
#include <hip/hip_runtime.h>
#include <hip/hip_bf16.h>
#include <hip/hip_fp16.h>

#define LL    3630
#define EPSV  1e-5f
#define NCH   57      // scan chunks (64-token, matches mamba_pre blocks)
#define CLEN  64

typedef short bf16x8 __attribute__((ext_vector_type(8)));
typedef float f32x4  __attribute__((ext_vector_type(4)));
typedef float f32x2  __attribute__((ext_vector_type(2)));
typedef float f32x16 __attribute__((ext_vector_type(16)));

__device__ __forceinline__ float bf2f(__hip_bfloat16 x){ return __bfloat162float(x); }
__device__ __forceinline__ __hip_bfloat16 f2bf(float x){ return __float2bfloat16(x); }
__device__ __forceinline__ float siluf(float x){ return x / (1.f + __expf(-x)); }
__device__ __forceinline__ float s2f(short s){ __hip_bfloat16 t = __builtin_bit_cast(__hip_bfloat16, s); return __bfloat162float(t); }
__device__ __forceinline__ short f2s(float x){ __hip_bfloat16 t = __float2bfloat16(x); return __builtin_bit_cast(short, t); }

// ======================= weight f32 -> bf16 =======================
__global__ __launch_bounds__(256) void convert_weights(
    const float* __restrict__ s0, const float* __restrict__ s1,
    const float* __restrict__ s2, const float* __restrict__ s3,
    const float* __restrict__ s4, const float* __restrict__ s5,
    const float* __restrict__ s6,
    __hip_bfloat16* __restrict__ dst)
{
  int gid = blockIdx.x*256 + threadIdx.x;
  float v;
  if      (gid <  65536) v = s0[gid];
  else if (gid < 327680) v = s1[gid-65536];
  else if (gid < 458752) v = s2[gid-327680];
  else if (gid < 491520) v = s3[gid-458752];
  else if (gid < 557056) v = s4[gid-491520];
  else if (gid < 622592) v = s5[gid-557056];
  else if (gid < 671744){
    int rel = gid - 622592;
    int layer = rel / 12288;
    int rr  = (rel % 12288) / 256;
    int ccol= rel & 255;
    v = (rr < 40) ? s6[layer*10240 + rr*256 + ccol] : 0.f;
  }
  else return;
  dst[gid] = f2bf(v);
}

// ======================= stem =======================
__global__ __launch_bounds__(256) void stem1_kernel(
    const float* __restrict__ x, const float* __restrict__ w,
    const float* __restrict__ g, const float* __restrict__ bb,
    const float* __restrict__ mm, const float* __restrict__ vv,
    float* __restrict__ out, int nb, int b0)
{
  int idx = blockIdx.x*256 + threadIdx.x;
  if (idx >= nb*123904) return;
  int j = idx % 11;
  int i = (idx/11) % 11;
  int t = (idx/121) % 32;
  int c = (idx/(121*32)) % 32;
  int b = idx/(121*32*32);
  const float* xp = x + ((b0+b)*32 + t)*169;
  const float* wp = w + c*9;
  float acc = 0.f;
  #pragma unroll
  for (int di=0; di<3; ++di)
    #pragma unroll
    for (int dj=0; dj<3; ++dj)
      acc += xp[(i+di)*13 + (j+dj)] * wp[di*3+dj];
  float s = g[c]*rsqrtf(vv[c]+EPSV);
  acc = acc*s + (bb[c]-mm[c]*s);
  out[idx] = fmaxf(acc, 0.f);
}

__global__ __launch_bounds__(256) void stem2_kernel(
    const float* __restrict__ h1, const float* __restrict__ w,
    const float* __restrict__ g, const float* __restrict__ bb,
    const float* __restrict__ mm, const float* __restrict__ vv,
    float* __restrict__ out, int nb)
{
  int idx = blockIdx.x*256 + threadIdx.x;
  if (idx >= nb*116160) return;
  int ij = idx % 121;
  int t  = (idx/121) % 30;
  int c  = (idx/(121*30)) % 32;
  int b  = idx/(121*30*32);
  const float* hp = h1 + ((b*32+c)*32)*121 + ij;
  const float* wp = w + c*3;
  float acc = 0.f;
  #pragma unroll
  for (int k=0;k<3;++k) acc += hp[(t+k)*121] * wp[k];
  float s = g[c]*rsqrtf(vv[c]+EPSV);
  acc = acc*s + (bb[c]-mm[c]*s);
  out[idx] = fmaxf(acc, 0.f);
}

// stem3 + fused LayerNorm (wave = one token, lane = channel)
__global__ __launch_bounds__(256) void stem3_kernel(
    const float* __restrict__ h2, const float* __restrict__ w,
    const float* __restrict__ lng, const float* __restrict__ lnb,
    __hip_bfloat16* __restrict__ xb, __hip_bfloat16* __restrict__ hx, int tokens)
{
  int gid = blockIdx.x*256 + threadIdx.x;
  int cc = gid & 63;
  int tok = gid >> 6;
  if (tok >= tokens) return;
  int ij = tok % 121;
  int t  = (tok/121) % 30;
  int b  = tok/LL;
  const float* hp = h2 + ((long)b*32)*30*121 + t*121 + ij;
  const float* wp = w + cc*32;
  float acc = 0.f;
  #pragma unroll
  for (int ci=0; ci<32; ++ci) acc += hp[ci*3630] * wp[ci];
  xb[(long)tok*64+cc] = f2bf(acc);
  float s = acc, q = acc*acc;
  #pragma unroll
  for (int m=1; m<64; m<<=1){ s += __shfl_xor(s,m); q += __shfl_xor(q,m); }
  float mean = s*(1.f/64.f);
  float var  = q*(1.f/64.f) - mean*mean;
  hx[(long)tok*64+cc] = f2bf((acc-mean)*rsqrtf(var+EPSV)*lng[cc] + lnb[cc]);
}

// ======================= bf16 MFMA GEMM: 128-row blocks + XCD-chunk swizzle =======================
template<int EPI>
__global__ __launch_bounds__(256) void gemm_bf16(
    const __hip_bfloat16* __restrict__ A, const __hip_bfloat16* __restrict__ W,
    int K, int N, int NH, int ny, int tokens,
    __hip_bfloat16* __restrict__ out1, __hip_bfloat16* __restrict__ out2,
    const float* __restrict__ bias, const __hip_bfloat16* __restrict__ gate,
    __hip_bfloat16* __restrict__ resid,
    const float* __restrict__ lng, const float* __restrict__ lnb)
{
  int w   = threadIdx.x >> 6;
  int lane= threadIdx.x & 63;
  int r16 = lane & 15;
  int kg  = lane >> 4;          // 0..3
  int nwg = gridDim.x;
  int orig = blockIdx.x;
  int q = nwg >> 3, r8 = nwg & 7;
  int xcd = orig & 7, off = orig >> 3;
  int wg = (xcd < r8 ? xcd*(q+1) : r8*(q+1) + (xcd-r8)*q) + off;
  int by = wg % ny;
  long bx = wg / ny;
  long m0 = bx*128 + w*32;
  int  n0 = by*64;
  long ra0 = m0 + r16;      if (ra0 > tokens-1) ra0 = tokens-1;
  long ra1 = m0 + 16 + r16; if (ra1 > tokens-1) ra1 = tokens-1;
  f32x4 acc[2][4] = { { {0,0,0,0},{0,0,0,0},{0,0,0,0},{0,0,0,0} },
                      { {0,0,0,0},{0,0,0,0},{0,0,0,0},{0,0,0,0} } };
  for (int k0 = 0; k0 < K; k0 += 32){
    bf16x8 a0 = *reinterpret_cast<const bf16x8*>(A + ra0*K + k0 + kg*8);
    bf16x8 a1 = *reinterpret_cast<const bf16x8*>(A + ra1*K + k0 + kg*8);
    #pragma unroll
    for (int f=0; f<4; ++f){
      bf16x8 b = *reinterpret_cast<const bf16x8*>(W + (long)(n0 + f*16 + r16)*K + k0 + kg*8);
      acc[0][f] = __builtin_amdgcn_mfma_f32_16x16x32_bf16(a0, b, acc[0][f], 0, 0, 0);
      acc[1][f] = __builtin_amdgcn_mfma_f32_16x16x32_bf16(a1, b, acc[1][f], 0, 0, 0);
    }
  }
  if (EPI == 5){
    float gv[4], bv[4], biasv[4];
    #pragma unroll
    for (int f=0; f<4; ++f){
      gv[f] = lng[f*16+r16]; bv[f] = lnb[f*16+r16];
      biasv[f] = bias ? bias[f*16+r16] : 0.f;
    }
    #pragma unroll
    for (int g2=0; g2<2; ++g2){
      #pragma unroll
      for (int r=0; r<4; ++r){
        long row = m0 + g2*16 + kg*4 + r;
        bool ok = row < tokens;
        long rowc = ok ? row : (tokens-1);
        float v[4]; float s = 0.f, qq = 0.f;
        #pragma unroll
        for (int f=0; f<4; ++f){
          float t = acc[g2][f][r] + biasv[f] + bf2f(resid[rowc*64 + f*16+r16]);
          v[f] = t; s += t; qq += t*t;
        }
        #pragma unroll
        for (int m=1; m<16; m<<=1){ s += __shfl_xor(s,m); qq += __shfl_xor(qq,m); }
        float mean = s*(1.f/64.f);
        float var  = qq*(1.f/64.f) - mean*mean;
        float rstd = rsqrtf(var+EPSV);
        if (ok){
          #pragma unroll
          for (int f=0; f<4; ++f){
            resid[row*64 + f*16+r16] = f2bf(v[f]);
            out1 [row*64 + f*16+r16] = f2bf((v[f]-mean)*rstd*gv[f] + bv[f]);
          }
        }
      }
    }
    return;
  }
  #pragma unroll
  for (int g2=0; g2<2; ++g2){
    #pragma unroll
    for (int f=0; f<4; ++f){
      int col = n0 + f*16 + r16;
      #pragma unroll
      for (int r=0; r<4; ++r){
        long row = m0 + g2*16 + kg*4 + r;
        if (row >= tokens) continue;
        float v = acc[g2][f][r];
        if (EPI == 0){
          if (col < NH) out1[row*NH + col] = f2bf(v);
          else          out2[row*NH + col - NH] = f2bf(siluf(v));
        } else if (EPI == 2){
          v += bias[col];
          v = 0.5f*v*(1.f + erff(v*0.70710678118f));
          out1[row*N + col] = f2bf(v);
        } else {
          out1[row*N + col] = f2bf(v * bf2f(gate[row*N + col]));
        }
      }
    }
  }
}

// ======================= depthwise conv3d 3x3x3 SAME + silu (2 channels/thread) =======================
__global__ __launch_bounds__(256) void dwconv3d_kernel(
    const __hip_bfloat16* __restrict__ xs, const float* __restrict__ w,
    const float* __restrict__ bias, __hip_bfloat16* __restrict__ seq, int tokens)
{
  long gid = (long)blockIdx.x*256 + threadIdx.x;
  int cp = gid & 63;              // channel pair
  long tok = gid >> 6;
  if (tok >= tokens) return;
  int c0 = cp*2;
  int j  = tok % 11;
  int i2 = (tok/11) % 11;
  int t  = (tok/121) % 30;
  long b = tok/LL;
  const float* wc0 = w + c0*27;
  const float* wc1 = wc0 + 27;
  float acc0 = bias[c0], acc1 = bias[c0+1];
  #pragma unroll
  for (int dt=0; dt<3; ++dt){
    int tt = t+dt-1; if (tt<0 || tt>=30) continue;
    #pragma unroll
    for (int di=0; di<3; ++di){
      int ii = i2+di-1; if (ii<0 || ii>=11) continue;
      #pragma unroll
      for (int dj=0; dj<3; ++dj){
        int jj = j+dj-1; if (jj<0 || jj>=11) continue;
        long t2 = (b*30+tt)*121 + ii*11 + jj;
        ushort2 pv = *reinterpret_cast<const ushort2*>(xs + t2*128 + c0);
        int tap = dt*9+di*3+dj;
        acc0 = fmaf(wc0[tap], s2f((short)pv.x), acc0);
        acc1 = fmaf(wc1[tap], s2f((short)pv.y), acc1);
      }
    }
  }
  ushort2 outv;
  outv.x = (unsigned short)f2s(siluf(acc0));
  outv.y = (unsigned short)f2s(siluf(acc1));
  *reinterpret_cast<ushort2*>(seq + tok*128 + c0) = outv;
}

// ======================= mamba_pre + scan pass1 fused (slim LDS: dt+B only) =======================
__global__ __launch_bounds__(256) void mamba_pre_scan(
    const __hip_bfloat16* __restrict__ xm,
    const float* __restrict__ cw, const float* __restrict__ cbv,
    const __hip_bfloat16* __restrict__ xpw_bf,
    const float* __restrict__ dtw, const float* __restrict__ dtbv,
    const float* __restrict__ Alog,
    __hip_bfloat16* __restrict__ ub,
    float* __restrict__ pre,
    float* __restrict__ hfin, float* __restrict__ sdt,
    int nb)
{
  __shared__ __hip_bfloat16 xcs[64][264];   // 33792 B
  __shared__ float presd[64][8];            //  2048 B (dt-rank)
  __shared__ float presb[64][16];           //  4096 B (B)  -> total 39936 B, 4 blocks/CU
  int s  = blockIdx.x / NCH;
  int ch = blockIdx.x % NCH;
  int p0 = ch*CLEN;
  int b  = s % nb;
  bool fwd = s < nb;
  int d = threadIdx.x;
  const long basex = (long)b*LL*256 + d;
  const long sLL = (long)s*LL;
  {
    float w0=cw[d*4], w1=cw[d*4+1], w2=cw[d*4+2], w3=cw[d*4+3], cb=cbv[d];
    float p1=0.f, p2=0.f, p3=0.f;
    if (p0-1 >= 0) p1 = bf2f(xm[basex + (long)(fwd ? p0-1 : LL-p0  )*256]);
    if (p0-2 >= 0) p2 = bf2f(xm[basex + (long)(fwd ? p0-2 : LL+1-p0)*256]);
    if (p0-3 >= 0) p3 = bf2f(xm[basex + (long)(fwd ? p0-3 : LL+2-p0)*256]);
    for (int t=0; t<64; ++t){
      int p = p0 + t;
      float xl = 0.f;
      if (p < LL) xl = bf2f(xm[basex + (long)(fwd ? p : LL-1-p)*256]);
      float xc = w3*xl + w2*p1 + w1*p2 + w0*p3 + cb;
      p3=p2; p2=p1; p1=xl;
      __hip_bfloat16 uv = f2bf(siluf(xc));
      xcs[t][d] = uv;
      if (p < LL) ub[(sLL + p)*256 + d] = uv;
    }
  }
  __syncthreads();
  {
    int w = threadIdx.x >> 6, lane = threadIdx.x & 63;
    int r16 = lane & 15, kg = lane >> 4;
    int t0 = w*16;
    f32x4 acc[3] = { {0,0,0,0},{0,0,0,0},{0,0,0,0} };
    for (int k0=0; k0<256; k0+=32){
      bf16x8 a = *reinterpret_cast<const bf16x8*>(&xcs[t0+r16][k0+kg*8]);
      #pragma unroll
      for (int f=0; f<3; ++f){
        bf16x8 bb = *reinterpret_cast<const bf16x8*>(xpw_bf + (f*16+r16)*256 + k0 + kg*8);
        acc[f] = __builtin_amdgcn_mfma_f32_16x16x32_bf16(a, bb, acc[f], 0, 0, 0);
      }
    }
    #pragma unroll
    for (int f=0; f<3; ++f){
      int col = f*16 + r16;
      #pragma unroll
      for (int r=0; r<4; ++r){
        int tl = t0 + kg*4 + r;
        int p = p0 + tl;
        if (col < 8)       presd[tl][col] = acc[f][r];
        else if (col < 24) presb[tl][col-8] = acc[f][r];
        if (col < 40 && p < LL) pre[(sLL + p)*40 + col] = acc[f][r];
      }
    }
  }
  __syncthreads();
  {
    int lim = LL - p0; if (lim > CLEN) lim = CLEN;
    f32x2 a2[8], h[8];
    #pragma unroll
    for (int k=0;k<8;++k){
      a2[k] = (f32x2){ -__expf(Alog[d*16+2*k])*1.44269504f,
                       -__expf(Alog[d*16+2*k+1])*1.44269504f };
      h[k] = (f32x2){0.f, 0.f};
    }
    float dw[8];
    #pragma unroll
    for (int r=0;r<8;++r) dw[r] = dtw[d*8+r];
    float dtb_d = dtbv[d];
    float sacc = 0.f;
    for (int t=0; t<lim; ++t){
      float u = bf2f(xcs[t][d]);
      float4 r0 = *reinterpret_cast<const float4*>(&presd[t][0]);
      float4 r1 = *reinterpret_cast<const float4*>(&presd[t][4]);
      float xacc = dtb_d;
      xacc = fmaf(r0.x,dw[0],fmaf(r0.y,dw[1],fmaf(r0.z,dw[2],fmaf(r0.w,dw[3],xacc))));
      xacc = fmaf(r1.x,dw[4],fmaf(r1.y,dw[5],fmaf(r1.z,dw[6],fmaf(r1.w,dw[7],xacc))));
      float dt = (xacc > 20.f) ? xacc : __logf(1.f + __expf(xacc));
      sacc += dt;
      float4 B0 = *reinterpret_cast<const float4*>(&presb[t][0]);
      float4 B1 = *reinterpret_cast<const float4*>(&presb[t][4]);
      float4 B2 = *reinterpret_cast<const float4*>(&presb[t][8]);
      float4 B3 = *reinterpret_cast<const float4*>(&presb[t][12]);
      float Bv[16] = {B0.x,B0.y,B0.z,B0.w,B1.x,B1.y,B1.z,B1.w,
                      B2.x,B2.y,B2.z,B2.w,B3.x,B3.y,B3.z,B3.w};
      f32x2 dt2  = (f32x2){dt, dt};
      float dtu = dt*u;
      f32x2 dtu2 = (f32x2){dtu, dtu};
      #pragma unroll
      for (int k=0;k<8;++k){
        f32x2 tt = dt2*a2[k];
        f32x2 e = (f32x2){ exp2f(tt.x), exp2f(tt.y) };
        f32x2 bk = (f32x2){ Bv[2*k], Bv[2*k+1] };
        h[k] = __builtin_elementwise_fma(e, h[k], dtu2*bk);
      }
    }
    long hbase = ((long)blockIdx.x*256 + d)*16;
    #pragma unroll
    for (int k=0;k<8;++k){ hfin[hbase+2*k] = h[k].x; hfin[hbase+2*k+1] = h[k].y; }
    sdt[(long)blockIdx.x*256 + d] = sacc;
  }
}

// sequential chunk combine (in-place: hfin becomes hinit)
__global__ __launch_bounds__(256) void scan_comb(
    const float* __restrict__ Alog,
    float* __restrict__ hfin, const float* __restrict__ sdt)
{
  int s = blockIdx.x >> 4, dg = blockIdx.x & 15;
  int d = dg*16 + (threadIdx.x >> 4), n = threadIdx.x & 15;
  float a2 = -__expf(Alog[d*16+n]) * 1.44269504f;
  float h = 0.f;
  for (int ch=0; ch<NCH; ++ch){
    long sc = (long)s*NCH + ch;
    long idx = (sc*256 + d)*16 + n;
    float hf = hfin[idx];
    float sd = sdt[sc*256 + d];
    hfin[idx] = h;
    h = exp2f(a2*sd)*h + hf;
  }
}

// pass2: rescan chunk from hinit; write raw y (+u*D) over ub in-place
__global__ __launch_bounds__(256) void scan_p2(
    __hip_bfloat16* __restrict__ ub,
    const float* __restrict__ pre,
    const float* __restrict__ dtw, const float* __restrict__ dtbv,
    const float* __restrict__ Alog, const float* __restrict__ Dv,
    const float* __restrict__ hinit)
{
  int d = threadIdx.x;
  int sc = blockIdx.x;
  int ch = sc % NCH, s = sc / NCH;
  int l0 = ch*CLEN;
  int lim = LL - l0; if (lim > CLEN) lim = CLEN;
  f32x2 a2[8], h[8];
  long hbase = ((long)sc*256 + d)*16;
  #pragma unroll
  for (int k=0;k<8;++k){
    a2[k] = (f32x2){ -__expf(Alog[d*16+2*k])*1.44269504f,
                     -__expf(Alog[d*16+2*k+1])*1.44269504f };
    h[k] = (f32x2){ hinit[hbase+2*k], hinit[hbase+2*k+1] };
  }
  float dw[8];
  #pragma unroll
  for (int r=0;r<8;++r) dw[r] = dtw[d*8+r];
  float dtb_d = dtbv[d];
  float dpv = Dv[d];
  long tok0 = (long)s*LL + l0;
  long ui = tok0*256 + d;
  long pi = tok0*40;
  #pragma unroll 2
  for (int l=0; l<lim; ++l){
    float u = bf2f(ub[ui]);
    float4 r0 = *reinterpret_cast<const float4*>(pre+pi);
    float4 r1 = *reinterpret_cast<const float4*>(pre+pi+4);
    float xacc = dtb_d;
    xacc = fmaf(r0.x,dw[0],fmaf(r0.y,dw[1],fmaf(r0.z,dw[2],fmaf(r0.w,dw[3],xacc))));
    xacc = fmaf(r1.x,dw[4],fmaf(r1.y,dw[5],fmaf(r1.z,dw[6],fmaf(r1.w,dw[7],xacc))));
    float dt = (xacc > 20.f) ? xacc : __logf(1.f + __expf(xacc));
    f32x16 B = *reinterpret_cast<const f32x16*>(pre+pi+8);
    f32x16 C = *reinterpret_cast<const f32x16*>(pre+pi+24);
    f32x2 dt2  = (f32x2){dt, dt};
    float dtu = dt*u;
    f32x2 dtu2 = (f32x2){dtu, dtu};
    f32x2 y2 = (f32x2){0.f, 0.f};
    #pragma unroll
    for (int k=0;k<8;++k){
      f32x2 t = dt2*a2[k];
      f32x2 e = (f32x2){ exp2f(t.x), exp2f(t.y) };
      f32x2 bk = (f32x2){ B[2*k], B[2*k+1] };
      f32x2 ck = (f32x2){ C[2*k], C[2*k+1] };
      h[k] = __builtin_elementwise_fma(e, h[k], dtu2*bk);
      y2 = __builtin_elementwise_fma(h[k], ck, y2);
    }
    float y = y2.x + y2.y;
    ub[ui] = f2bf(y + u*dpv);
    ui += 256; pi += 40;
  }
}

// ======================= combine fwd/bwd + zm gate (bf16x8 vectorized) =======================
__global__ __launch_bounds__(256) void combine_kernel(
    const __hip_bfloat16* __restrict__ yb, const __hip_bfloat16* __restrict__ zm,
    __hip_bfloat16* __restrict__ ycomb, int tokens, int nb)
{
  long gid = (long)blockIdx.x*256 + threadIdx.x;   // one per 8 channels
  long tok = gid >> 5;
  if (tok >= tokens) return;
  int c8 = (gid & 31) * 8;
  long l = tok % LL, b = tok / LL;
  bf16x8 vf = *reinterpret_cast<const bf16x8*>(yb + ( b*LL + l)*256 + c8);
  bf16x8 vb = *reinterpret_cast<const bf16x8*>(yb + ((nb+b)*LL + (LL-1-l))*256 + c8);
  bf16x8 zz = *reinterpret_cast<const bf16x8*>(zm + tok*256 + c8);
  bf16x8 out;
  #pragma unroll
  for (int k=0;k<8;++k){
    float r = (s2f(vf[k]) + s2f(vb[k])) * s2f(zz[k]);
    out[k] = f2s(r);
  }
  *reinterpret_cast<bf16x8*>(ycomb + tok*256 + c8) = out;
}

// ======================= head: two-stage mean + linear =======================
__global__ __launch_bounds__(256) void head1_kernel(
    const __hip_bfloat16* __restrict__ xb, float* __restrict__ hp)
{
  __shared__ float partial[4][64];
  int b = blockIdx.x / 30, ch = blockIdx.x % 30;
  int d = threadIdx.x & 63, part = threadIdx.x >> 6;
  float acc = 0.f;
  int lend = (ch+1)*121;
  for (int l = ch*121 + part; l < lend; l += 4)
    acc += bf2f(xb[((long)b*LL + l)*64 + d]);
  partial[part][d] = acc;
  __syncthreads();
  if (part == 0)
    hp[(b*30 + ch)*64 + d] = partial[0][d]+partial[1][d]+partial[2][d]+partial[3][d];
}

__global__ __launch_bounds__(64) void head2_kernel(
    const float* __restrict__ hp, const float* __restrict__ hw,
    const float* __restrict__ hb, float* __restrict__ out, int b0)
{
  __shared__ float feat[64];
  int b = blockIdx.x;
  int d = threadIdx.x;
  float acc = 0.f;
  #pragma unroll
  for (int ch=0; ch<30; ++ch) acc += hp[(b*30+ch)*64 + d];
  float f = acc * (1.f/3630.f);
  feat[d] = f;
  out[512 + (b0+b)*64 + d] = f;
  __syncthreads();
  if (d < 16){
    float a2 = hb[d];
    #pragma unroll
    for (int k=0; k<64; ++k) a2 += feat[k]*hw[d*64+k];
    out[(b0+b)*16 + d] = a2;
  }
}

// ======================= launch =======================
extern "C" void kernel_launch(void* const* d_in, const int* in_sizes, int n_in,
                              void* d_out, int out_size, void* d_ws, size_t ws_size,
                              hipStream_t stream)
{
  const float* x        = (const float*)d_in[0];
  const float* sconv_w  = (const float*)d_in[1];
  const float* bn1_g    = (const float*)d_in[2];
  const float* bn1_b    = (const float*)d_in[3];
  const float* bn1_m    = (const float*)d_in[4];
  const float* bn1_v    = (const float*)d_in[5];
  const float* tconv_w  = (const float*)d_in[6];
  const float* bn2_g    = (const float*)d_in[7];
  const float* bn2_b    = (const float*)d_in[8];
  const float* bn2_m    = (const float*)d_in[9];
  const float* bn2_v    = (const float*)d_in[10];
  const float* last_w   = (const float*)d_in[11];
  const float* ln1_g    = (const float*)d_in[12];
  const float* ln1_b    = (const float*)d_in[13];
  const float* in_proj_w= (const float*)d_in[14];
  const float* conv3d_w = (const float*)d_in[15];
  const float* conv3d_b = (const float*)d_in[16];
  const float* m_in_w   = (const float*)d_in[17];
  const float* m_conv_w = (const float*)d_in[18];
  const float* m_conv_b = (const float*)d_in[19];
  const float* m_xproj_w= (const float*)d_in[20];
  const float* m_dtproj_w=(const float*)d_in[21];
  const float* m_dtproj_b=(const float*)d_in[22];
  const float* m_Alog   = (const float*)d_in[23];
  const float* m_D      = (const float*)d_in[24];
  const float* m_out_w  = (const float*)d_in[25];
  const float* out_proj_w=(const float*)d_in[26];
  const float* ln2_g    = (const float*)d_in[27];
  const float* ln2_b    = (const float*)d_in[28];
  const float* fc1_w    = (const float*)d_in[29];
  const float* fc1_b    = (const float*)d_in[30];
  const float* fc2_w    = (const float*)d_in[31];
  const float* fc2_b    = (const float*)d_in[32];
  const float* head_w   = (const float*)d_in[33];
  const float* head_b   = (const float*)d_in[34];

  const size_t WB = 1345536;
  int nb = 1;
  for (int cand = 32; cand >= 1; cand >>= 1){
    size_t TPc = (((size_t)cand*LL + 63)/64)*64;
    size_t S2c = (size_t)2*cand*LL;
    size_t need = WB + TPc*2048 + S2c*672;
    if (need <= ws_size){ nb = cand; break; }
  }
  const size_t TP  = (((size_t)nb*LL + 63)/64)*64;
  const int S2  = 2*nb;
  const size_t S2T = (size_t)S2*LL;
  const int tokens = nb*LL;

  char* ws = (char*)d_ws;
  __hip_bfloat16* wbf   = (__hip_bfloat16*)(ws);
  size_t o = WB;
  __hip_bfloat16* xb    = (__hip_bfloat16*)(ws + o); o += TP*128;
  __hip_bfloat16* hx    = (__hip_bfloat16*)(ws + o); o += TP*128;
  float*          hp    = (float*)hx;
  float*          hfin  = (float*)hx;       // spans hx+xs+seq during scan phase
  __hip_bfloat16* xs    = (__hip_bfloat16*)(ws + o); o += TP*256;
  __hip_bfloat16* seq   = (__hip_bfloat16*)(ws + o); o += TP*256;
  __hip_bfloat16* ycomb = xs;
  __hip_bfloat16* zblk  = (__hip_bfloat16*)(ws + o); o += TP*256;
  __hip_bfloat16* xm    = (__hip_bfloat16*)(ws + o);
  __hip_bfloat16* yo    = xm;                        o += TP*512;
  __hip_bfloat16* zm    = (__hip_bfloat16*)(ws + o);
  __hip_bfloat16* h2m   = zm;                        o += TP*512;
  float*          pre   = (float*)(ws + o);          o += S2T*160;
  __hip_bfloat16* ybuf  = (__hip_bfloat16*)(ws + o);
  float*          h1s   = (float*)(ws + o);
  float*          h2s   = (float*)(ws + o + (size_t)nb*495616);
  float*          sdtb  = hfin + (size_t)S2*NCH*4096;

  convert_weights<<<2624, 256, 0, stream>>>(in_proj_w, m_in_w, m_out_w, out_proj_w,
                                            fc1_w, fc2_w, m_xproj_w, wbf);

  const int gM2 = (int)((TP + 127)/128);

  for (int b0 = 0; b0 < 32; b0 += nb){
    stem1_kernel<<<nb*484, 256, 0, stream>>>(x, sconv_w, bn1_g, bn1_b, bn1_m, bn1_v, h1s, nb, b0);
    stem2_kernel<<<(nb*116160+255)/256, 256, 0, stream>>>(h1s, tconv_w, bn2_g, bn2_b, bn2_m, bn2_v, h2s, nb);
    stem3_kernel<<<(tokens*64+255)/256, 256, 0, stream>>>(h2s, last_w, ln1_g, ln1_b, xb, hx, tokens);

    for (int i = 0; i < 4; ++i){
      gemm_bf16<0><<<gM2*4, 256, 0, stream>>>(hx, wbf + i*16384, 64, 256, 128, 4, tokens,
                                              xs, zblk, nullptr, nullptr, nullptr, nullptr, nullptr);
      dwconv3d_kernel<<<(tokens*64+255)/256, 256, 0, stream>>>(xs, conv3d_w + i*3456, conv3d_b + i*128, seq, tokens);
      gemm_bf16<0><<<gM2*8, 256, 0, stream>>>(seq, wbf + 65536 + i*65536, 128, 512, 256, 8, tokens,
                                              xm, zm, nullptr, nullptr, nullptr, nullptr, nullptr);
      mamba_pre_scan<<<S2*NCH, 256, 0, stream>>>(xm, m_conv_w + i*1024, m_conv_b + i*256,
                                                 wbf + 622592 + i*12288,
                                                 m_dtproj_w + i*2048, m_dtproj_b + i*256,
                                                 m_Alog + i*4096,
                                                 ybuf, pre, hfin, sdtb, nb);
      scan_comb<<<S2*16, 256, 0, stream>>>(m_Alog + i*4096, hfin, sdtb);
      scan_p2<<<S2*NCH, 256, 0, stream>>>(ybuf, pre, m_dtproj_w + i*2048, m_dtproj_b + i*256,
                                          m_Alog + i*4096, m_D + i*256, hfin);
      combine_kernel<<<(tokens*32+255)/256, 256, 0, stream>>>(ybuf, zm, ycomb, tokens, nb);
      gemm_bf16<4><<<gM2*2, 256, 0, stream>>>(ycomb, wbf + 327680 + i*32768, 256, 128, 0, 2, tokens,
                                              yo, nullptr, nullptr, zblk, nullptr, nullptr, nullptr);
      gemm_bf16<5><<<gM2, 256, 0, stream>>>(yo, wbf + 458752 + i*8192, 128, 64, 0, 1, tokens,
                                            hx, nullptr, nullptr, nullptr, xb,
                                            ln2_g + i*64, ln2_b + i*64);
      gemm_bf16<2><<<gM2*4, 256, 0, stream>>>(hx, wbf + 491520 + i*16384, 64, 256, 0, 4, tokens,
                                              h2m, nullptr, fc1_b + i*256, nullptr, nullptr, nullptr, nullptr);
      int inext = (i < 3) ? i+1 : 3;
      gemm_bf16<5><<<gM2, 256, 0, stream>>>(h2m, wbf + 557056 + i*16384, 256, 64, 0, 1, tokens,
                                            hx, nullptr, fc2_b + i*64, nullptr, xb,
                                            ln1_g + inext*64, ln1_b + inext*64);
    }
    head1_kernel<<<nb*30, 256, 0, stream>>>(xb, hp);
    head2_kernel<<<nb, 64, 0, stream>>>(hp, head_w, head_b, (float*)d_out, b0);
  }
}